// Round 1
// 566.713 us; speedup vs baseline: 1.3508x; 1.3508x over previous
//
#include <hip/hip_runtime.h>
#include <cstddef>

// ---------------------------------------------------------------------------
// Decagon pipeline, fp32, algebraically collapsed output layers.
// Key identity: hardshrink(v, 1e-6) == v to within 1e-6, so
//   out2[t] = hshrink( xd[t] @ oW1 @ W2s + oB1 @ W2s + oB2s )
//           = hshrink( PP[a] + QQ[b] + Cvec )
// with PP/QQ precomputed over the 1000 drugs (not the 150k pairs).
//
// R1: replace the float-atomic edge scatter (3.9M atomicAdds -> 122 MB of
// atomic write-through HBM traffic, 237 us, VALUBusy 0.4%) with a bucketed
// aggregation: count degrees -> prefix scan -> fill src-index buckets ->
// per-dst block sum with no atomics.
// ---------------------------------------------------------------------------

__device__ __forceinline__ float hshrink(float v) {
    return (fabsf(v) > 1e-6f) ? v : 0.0f;
}

// C = relu(A @ W + bias), A:(M,K), W:(K,128), C:(M,128). 8 rows/block.
__global__ __launch_bounds__(256) void k_mlp(const float* __restrict__ A,
                                             const float* __restrict__ W,
                                             const float* __restrict__ bias,
                                             float* __restrict__ C, int M, int K) {
    __shared__ float As[8 * 128];
    const int tid = threadIdx.x;
    const int r0  = blockIdx.x * 8;
    const int col = tid & 127;
    const int rh  = tid >> 7;   // 0/1 -> rows rh*4 .. rh*4+3
    float acc[4] = {0.f, 0.f, 0.f, 0.f};

    const int sr  = tid >> 5;        // staging row 0..7
    const int sc4 = (tid & 31) * 4;  // staging col (float4)
    const int ra  = min(r0 + sr, M - 1);

    for (int kc = 0; kc < K; kc += 128) {
        __syncthreads();
        float4 v = *(const float4*)(A + (size_t)ra * K + kc + sc4);
        *(float4*)&As[sr * 128 + sc4] = v;
        __syncthreads();
        for (int k = 0; k < 128; k += 4) {
            float w0 = W[(size_t)(kc + k + 0) * 128 + col];
            float w1 = W[(size_t)(kc + k + 1) * 128 + col];
            float w2 = W[(size_t)(kc + k + 2) * 128 + col];
            float w3 = W[(size_t)(kc + k + 3) * 128 + col];
#pragma unroll
            for (int r = 0; r < 4; r++) {
                float4 av = *(const float4*)&As[(rh * 4 + r) * 128 + k];
                acc[r] = fmaf(av.x, w0, acc[r]);
                acc[r] = fmaf(av.y, w1, acc[r]);
                acc[r] = fmaf(av.z, w2, acc[r]);
                acc[r] = fmaf(av.w, w3, acc[r]);
            }
        }
    }
    float bb = bias[col];
#pragma unroll
    for (int r = 0; r < 4; r++) {
        int row = r0 + rh * 4 + r;
        if (row < M) C[(size_t)row * 128 + col] = fmaxf(acc[r] + bb, 0.f);
    }
}

// R1 pass A: deg[dst]++ for edges with dst < nD (int atomics, ~30 per counter).
__global__ __launch_bounds__(256) void k_deg(const int* __restrict__ ei,
                                             int* __restrict__ deg, int E, int nD) {
    int e = blockIdx.x * 256 + threadIdx.x;
    if (e >= E) return;
    int dst = ei[E + e];
    if (dst < nD) atomicAdd(deg + dst, 1);
}

// R1 pass B: single-block Hillis-Steele scan of deg[0..nD) -> off (exclusive,
// nD+1 entries) and cursor (= off copy for the fill pass). nD <= 1024.
__global__ __launch_bounds__(1024) void k_scan(const int* __restrict__ deg,
                                               int* __restrict__ off,
                                               int* __restrict__ cursor, int nD) {
    __shared__ int s[1024];
    int t = threadIdx.x;
    int v = (t < nD) ? deg[t] : 0;
    s[t] = v;
    __syncthreads();
    for (int o = 1; o < 1024; o <<= 1) {
        int add = (t >= o) ? s[t - o] : 0;
        __syncthreads();
        s[t] += add;
        __syncthreads();
    }
    int excl = s[t] - v;
    if (t < nD) {
        off[t]    = excl;
        cursor[t] = excl;
    }
    if (t == nD - 1) off[nD] = s[t];
}

// R1 pass C: scatter src indices of surviving edges into per-dst buckets.
__global__ __launch_bounds__(256) void k_fill(const int* __restrict__ ei,
                                              int* __restrict__ cursor,
                                              int* __restrict__ srcIdx, int E, int nD) {
    int e = blockIdx.x * 256 + threadIdx.x;
    if (e >= E) return;
    int dst = ei[E + e];
    if (dst >= nD) return;
    int pos = atomicAdd(cursor + dst, 1);
    srcIdx[pos] = ei[e];
}

// R1 pass D: one block per dst drug, 128 threads (one per feature col).
// Plain-FMA sum over the bucket -> agg, degree -> cnt. No atomics.
__global__ __launch_bounds__(128) void k_agg(const int* __restrict__ off,
                                             const int* __restrict__ srcIdx,
                                             const float* __restrict__ xF,
                                             float* __restrict__ agg,
                                             float* __restrict__ cnt, int nD) {
    int d = blockIdx.x;
    int c = threadIdx.x;
    int s0 = off[d], s1 = off[d + 1];
    float acc = 0.f;
    int j = s0;
    for (; j + 4 <= s1; j += 4) {
        int i0 = srcIdx[j + 0];
        int i1 = srcIdx[j + 1];
        int i2 = srcIdx[j + 2];
        int i3 = srcIdx[j + 3];
        acc += xF[(size_t)i0 * 128 + c];
        acc += xF[(size_t)i1 * 128 + c];
        acc += xF[(size_t)i2 * 128 + c];
        acc += xF[(size_t)i3 * 128 + c];
    }
    for (; j < s1; j++) acc += xF[(size_t)srcIdx[j] * 128 + c];
    agg[(size_t)d * 128 + c] = acc;
    if (c == 0) cnt[d] = (float)(s1 - s0);
}

// finalX = relu((agg/max(cnt,1)) @ Wl + bl + xF @ Wr), rows 0..M-1. 8 rows/block.
__global__ __launch_bounds__(256) void k_sage(const float* __restrict__ agg,
                                              const float* __restrict__ cnt,
                                              const float* __restrict__ xF,
                                              const float* __restrict__ Wl,
                                              const float* __restrict__ bl,
                                              const float* __restrict__ Wr,
                                              float* __restrict__ fX, int M) {
    __shared__ float ms[8 * 128];
    __shared__ float xs[8 * 128];
    const int tid = threadIdx.x;
    const int r0  = blockIdx.x * 8;
    const int col = tid & 127;
    const int rh  = tid >> 7;

    const int sr  = tid >> 5;
    const int sc4 = (tid & 31) * 4;
    const int ra  = min(r0 + sr, M - 1);
    float inv = 1.0f / fmaxf(cnt[ra], 1.0f);
    float4 av = *(const float4*)(agg + (size_t)ra * 128 + sc4);
    av.x *= inv; av.y *= inv; av.z *= inv; av.w *= inv;
    *(float4*)&ms[sr * 128 + sc4] = av;
    *(float4*)&xs[sr * 128 + sc4] = *(const float4*)(xF + (size_t)ra * 128 + sc4);
    __syncthreads();

    float acc[4] = {0.f, 0.f, 0.f, 0.f};
    for (int k = 0; k < 128; k += 4) {
#pragma unroll
        for (int u = 0; u < 4; u++) {
            float wl = Wl[(size_t)(k + u) * 128 + col];
            float wr = Wr[(size_t)(k + u) * 128 + col];
#pragma unroll
            for (int r = 0; r < 4; r++) {
                acc[r] = fmaf(ms[(rh * 4 + r) * 128 + k + u], wl, acc[r]);
                acc[r] = fmaf(xs[(rh * 4 + r) * 128 + k + u], wr, acc[r]);
            }
        }
    }
    float bb = bl[col];
#pragma unroll
    for (int r = 0; r < 4; r++) {
        int row = r0 + rh * 4 + r;
        if (row < M) fX[(size_t)row * 128 + col] = fmaxf(acc[r] + bb, 0.f);
    }
}

// Gather outW2[:, sampleSes] into padded (128 x 512) + outB2[sampleSes] into 512.
__global__ __launch_bounds__(256) void k_w2g(const float* __restrict__ oW2,
                                             const float* __restrict__ oB2,
                                             const int* __restrict__ sSes,
                                             float* __restrict__ W2p,
                                             float* __restrict__ B2p, int nSe, int S) {
    int t = blockIdx.x * 256 + threadIdx.x;
    if (t < 128 * 512) {
        int k = t >> 9, j = t & 511;
        W2p[t] = (j < S) ? oW2[(size_t)k * nSe + sSes[j]] : 0.f;
    } else {
        int j = t - 128 * 512;
        if (j < 512) B2p[j] = (j < S) ? oB2[sSes[j]] : 0.f;
    }
}

// Generic small GEMM: C(M x 512) = A(M x 128) @ B(128 x 512), no activation.
// Block tile 16 rows x 128 cols; grid = (ceil(M/16), 4). ldb/ldc parametric.
__global__ __launch_bounds__(256) void k_g16(const float* __restrict__ A,
                                             const float* __restrict__ B,
                                             float* __restrict__ C, int M,
                                             int ldb, int ldc) {
    __shared__ float As[16 * 128];
    const int tid = threadIdx.x;
    const int r0  = blockIdx.x * 16;
    const int cb  = blockIdx.y;           // 0..3, 128 cols each
    const int c4  = (tid & 31) * 4;       // col offset within 128
    const int rg  = tid >> 5;             // 0..7 -> rows rg*2, rg*2+1

#pragma unroll
    for (int l = 0; l < 2; l++) {
        int idx = tid + l * 256;
        int row = idx >> 5, cc = (idx & 31) * 4;
        int ra  = min(r0 + row, M - 1);
        *(float4*)&As[row * 128 + cc] = *(const float4*)(A + (size_t)ra * 128 + cc);
    }
    __syncthreads();

    const float* Bp = B + cb * 128 + c4;
    float acc[2][4] = {};
    for (int k = 0; k < 128; k += 4) {
        float4 a0 = *(const float4*)&As[(rg * 2 + 0) * 128 + k];
        float4 a1 = *(const float4*)&As[(rg * 2 + 1) * 128 + k];
        const float* pa0 = &a0.x;
        const float* pa1 = &a1.x;
#pragma unroll
        for (int u = 0; u < 4; u++) {
            float4 wv = *(const float4*)(Bp + (size_t)(k + u) * ldb);
            float v0 = pa0[u], v1 = pa1[u];
            acc[0][0] = fmaf(v0, wv.x, acc[0][0]);
            acc[0][1] = fmaf(v0, wv.y, acc[0][1]);
            acc[0][2] = fmaf(v0, wv.z, acc[0][2]);
            acc[0][3] = fmaf(v0, wv.w, acc[0][3]);
            acc[1][0] = fmaf(v1, wv.x, acc[1][0]);
            acc[1][1] = fmaf(v1, wv.y, acc[1][1]);
            acc[1][2] = fmaf(v1, wv.z, acc[1][2]);
            acc[1][3] = fmaf(v1, wv.w, acc[1][3]);
        }
    }
#pragma unroll
    for (int r = 0; r < 2; r++) {
        int row = r0 + rg * 2 + r;
        if (row < M) {
            float4 o = {acc[r][0], acc[r][1], acc[r][2], acc[r][3]};
            *(float4*)(C + (size_t)row * ldc + cb * 128 + c4) = o;
        }
    }
}

// Cvec[j] = sum_k oB1[k] * W2p[k][j] + B2p[j], j in [0,512)
__global__ __launch_bounds__(256) void k_cvec(const float* __restrict__ oB1,
                                              const float* __restrict__ W2p,
                                              const float* __restrict__ B2p,
                                              float* __restrict__ Cvec) {
    int j = blockIdx.x * 256 + threadIdx.x;
    if (j >= 512) return;
    float s = B2p[j];
    for (int k = 0; k < 128; k++) s = fmaf(oB1[k], W2p[k * 512 + j], s);
    Cvec[j] = s;
}

// out[t][j] = hshrink(PP[a][j] + QQ[b][j] + Cvec[j]); PPQQ is (1000 x 1024):
// PP in cols [0,512), QQ in cols [512,1024). 2 tpl rows per block.
__global__ __launch_bounds__(256) void k_final(const int* __restrict__ tpl,
                                               const float* __restrict__ PPQQ,
                                               const float* __restrict__ Cvec,
                                               float* __restrict__ out, int T, int S) {
    int t = blockIdx.x * 2 + (threadIdx.x >> 7);
    int i = threadIdx.x & 127;
    int nf4 = S >> 2;  // 125 for S=500
    if (t >= T || i >= nf4) return;
    int a = tpl[2 * t];
    int b = tpl[2 * t + 1];
    const float4* P = (const float4*)(PPQQ + (size_t)a * 1024) + i;
    const float4* Q = (const float4*)(PPQQ + (size_t)b * 1024 + 512) + i;
    float4 p = *P, q = *Q;
    float4 c = ((const float4*)Cvec)[i];
    float o0 = hshrink(p.x + q.x + c.x);
    float o1 = hshrink(p.y + q.y + c.y);
    float o2 = hshrink(p.z + q.z + c.z);
    float o3 = hshrink(p.w + q.w + c.w);
    float* po = out + (size_t)t * S + i * 4;
    // nontemporal: keep the 4 MB PPQQ working set resident in L2
    __builtin_nontemporal_store(o0, po + 0);
    __builtin_nontemporal_store(o1, po + 1);
    __builtin_nontemporal_store(o2, po + 2);
    __builtin_nontemporal_store(o3, po + 3);
}

extern "C" void kernel_launch(void* const* d_in, const int* in_sizes, int n_in,
                              void* d_out, int out_size, void* d_ws, size_t ws_size,
                              hipStream_t stream) {
    const float* dF   = (const float*)d_in[0];
    const int*   ei   = (const int*)d_in[1];
    const int*   tpl  = (const int*)d_in[2];
    const int*   sSes = (const int*)d_in[3];
    const float* W1   = (const float*)d_in[4];
    const float* b1   = (const float*)d_in[5];
    const float* W2   = (const float*)d_in[6];
    const float* b2   = (const float*)d_in[7];
    const float* pE   = (const float*)d_in[8];
    const float* sWl  = (const float*)d_in[9];
    const float* sBl  = (const float*)d_in[10];
    const float* sWr  = (const float*)d_in[11];
    const float* oW1  = (const float*)d_in[12];
    const float* oB1  = (const float*)d_in[13];
    const float* oW2  = (const float*)d_in[14];
    const float* oB2  = (const float*)d_in[15];

    const int D    = 128;
    const int F    = in_sizes[4] / D;   // 2048
    const int nD   = in_sizes[0] / F;   // 1000
    const int E    = in_sizes[1] / 2;   // 640000
    const int T    = in_sizes[2] / 2;   // 150000
    const int S    = in_sizes[3];       // 500
    const int nPro = in_sizes[8] / D;   // 20000
    const int nSe  = in_sizes[15];      // 964

    float* ws   = (float*)d_ws;
    float* xF   = ws;                               // (nD+nPro)*128
    float* h1   = xF + (size_t)(nD + nPro) * D;     // nD*128
    float* agg  = h1 + (size_t)nD * D;              // nD*128
    float* cnt  = agg + (size_t)nD * D;             // nD (padded to 1024)
    float* fX   = cnt + 1024;                       // nD*128
    float* W2p  = fX + (size_t)nD * D;              // 128*512
    float* B2p  = W2p + 128 * 512;                  // 512
    float* M2   = B2p + 512;                        // 256*512
    float* Cvec = M2 + 256 * 512;                   // 512
    float* PPQQ = Cvec + 512;                       // nD*1024
    int* deg    = (int*)(PPQQ + (size_t)nD * 1024); // 1024
    int* off    = deg + 1024;                       // 1024 + 1
    int* cursor = off + 1025;                       // 1024
    int* srcIdx = cursor + 1024;                    // E

    // MLP: h1 = relu(dF@W1+b1); xF[:nD] = relu(h1@W2+b2)
    k_mlp<<<(nD + 7) / 8, 256, 0, stream>>>(dF, W1, b1, h1, nD, F);
    k_mlp<<<(nD + 7) / 8, 256, 0, stream>>>(h1, W2, b2, xF, nD, D);
    // xF[nD:] = proteinEmb
    hipMemcpyAsync(xF + (size_t)nD * D, pE, (size_t)nPro * D * sizeof(float),
                   hipMemcpyDeviceToDevice, stream);
    // bucketed edge aggregation (replaces float-atomic scatter)
    hipMemsetAsync(deg, 0, 1024 * sizeof(int), stream);
    k_deg<<<(E + 255) / 256, 256, 0, stream>>>(ei, deg, E, nD);
    k_scan<<<1, 1024, 0, stream>>>(deg, off, cursor, nD);
    k_fill<<<(E + 255) / 256, 256, 0, stream>>>(ei, cursor, srcIdx, E, nD);
    k_agg<<<nD, 128, 0, stream>>>(off, srcIdx, xF, agg, cnt, nD);
    // SAGE rows 0..nD-1 -> fX
    k_sage<<<(nD + 7) / 8, 256, 0, stream>>>(agg, cnt, xF, sWl, sBl, sWr, fX, nD);
    // gather sampled outW2 columns (padded to 512)
    k_w2g<<<(128 * 512 + 512 + 255) / 256, 256, 0, stream>>>(oW2, oB2, sSes, W2p, B2p,
                                                             nSe, S);
    // M2 = outW1 (256x128) @ W2p (128x512)
    {
        dim3 g((256 + 15) / 16, 4);
        k_g16<<<g, 256, 0, stream>>>(oW1, W2p, M2, 256, 512, 512);
    }
    // Cvec = oB1 @ W2p + B2p
    k_cvec<<<2, 256, 0, stream>>>(oB1, W2p, B2p, Cvec);
    // PP = fX @ M2[0:128]   -> PPQQ cols [0,512)
    // QQ = fX @ M2[128:256] -> PPQQ cols [512,1024)
    {
        dim3 g((nD + 15) / 16, 4);
        k_g16<<<g, 256, 0, stream>>>(fX, M2, PPQQ, nD, 512, 1024);
        k_g16<<<g, 256, 0, stream>>>(fX, M2 + (size_t)128 * 512, PPQQ + 512, nD, 512,
                                     1024);
    }
    // final streaming epilogue
    k_final<<<(T + 1) / 2, 256, 0, stream>>>(tpl, PPQQ, Cvec, (float*)d_out, T, S);
}

// Round 2
// 509.127 us; speedup vs baseline: 1.5036x; 1.1131x over previous
//
#include <hip/hip_runtime.h>
#include <cstddef>

// ---------------------------------------------------------------------------
// Decagon pipeline, fp32, algebraically collapsed output layers.
// Key identity: hardshrink(v, 1e-6) == v to within 1e-6, so
//   out2[t] = hshrink( xd[t] @ oW1 @ W2s + oB1 @ W2s + oB2s )
//           = hshrink( PP'[a] + QQ[b] ),  PP' = fX@M2_hi + Cvec folded in.
//
// R1: bucketed edge aggregation (degree count -> scan -> fill -> block sum)
//     replacing 3.9M float atomicAdds. 765 -> 567 us.
// R2: layer-1 MLP was latency-bound (2048 scalar stride-512B global W loads
//     per thread, 125 blocks, ~2 waves/SIMD). Split-K=4 + LDS-staged W
//     panels; partial reduce fused into layer-2 staging. W staged in LDS for
//     sage and the PP/QQ GEMM too; PP/QQ merged into one launch with Cvec
//     folded into PP; pE memcpy dropped (k_agg gathers from both sources).
// ---------------------------------------------------------------------------

__device__ __forceinline__ float hshrink(float v) {
    return (fabsf(v) > 1e-6f) ? v : 0.0f;
}

// Layer-1 partial GEMM: Cp[sk][row][col] = A[row, sk*KS : (sk+1)*KS] @ W-chunk.
// 16 rows/block, W staged in LDS as 64x128 panels. grid (ceil(M/16), SK).
__global__ __launch_bounds__(256) void k_mlp1(const float* __restrict__ A,
                                              const float* __restrict__ W,
                                              float* __restrict__ Cp, int M, int K,
                                              int KS) {
    __shared__ float As[16 * 64];
    __shared__ float Ws[64 * 128];
    const int tid = threadIdx.x;
    const int r0  = blockIdx.x * 16;
    const int sk  = blockIdx.y;
    const int col = tid & 127;
    const int rh  = tid >> 7;  // 0/1 -> rows rh*8 .. rh*8+7
    float acc[8] = {};

    const int sr  = tid >> 4;        // A-stage row 0..15
    const int sc4 = (tid & 15) * 4;  // A-stage col (float4), 0..60
    const int ra  = min(r0 + sr, M - 1);
    const int k0  = sk * KS;

    for (int kc = k0; kc < k0 + KS; kc += 64) {
        // A tile 16x64
        *(float4*)&As[sr * 64 + sc4] = *(const float4*)(A + (size_t)ra * K + kc + sc4);
        // W tile 64x128 (coalesced float4)
#pragma unroll
        for (int l = 0; l < 8; l++) {
            int idx = tid + l * 256;       // float4 index 0..2047
            int wr  = idx >> 5;            // 0..63
            int wc  = (idx & 31) * 4;
            *(float4*)&Ws[wr * 128 + wc] =
                *(const float4*)(W + (size_t)(kc + wr) * 128 + wc);
        }
        __syncthreads();
        for (int k = 0; k < 64; k += 4) {
            float w0 = Ws[(k + 0) * 128 + col];
            float w1 = Ws[(k + 1) * 128 + col];
            float w2 = Ws[(k + 2) * 128 + col];
            float w3 = Ws[(k + 3) * 128 + col];
#pragma unroll
            for (int r = 0; r < 8; r++) {
                float4 av = *(const float4*)&As[(rh * 8 + r) * 64 + k];
                acc[r] = fmaf(av.x, w0, acc[r]);
                acc[r] = fmaf(av.y, w1, acc[r]);
                acc[r] = fmaf(av.z, w2, acc[r]);
                acc[r] = fmaf(av.w, w3, acc[r]);
            }
        }
        __syncthreads();
    }
#pragma unroll
    for (int r = 0; r < 8; r++) {
        int row = r0 + rh * 8 + r;
        if (row < M) Cp[((size_t)sk * M + row) * 128 + col] = acc[r];
    }
}

// Layer-2: stage A = relu(sum_sk Cp + b1), W2 staged in LDS (two 64-row panels),
// write xFd = relu(A @ W2 + b2). 8 rows/block.
__global__ __launch_bounds__(256) void k_mlp2(const float* __restrict__ Cp,
                                              const float* __restrict__ b1v,
                                              const float* __restrict__ W,
                                              const float* __restrict__ b2v,
                                              float* __restrict__ Cout, int M, int SK) {
    __shared__ float As[8 * 128];
    __shared__ float Ws[64 * 128];
    const int tid = threadIdx.x;
    const int r0  = blockIdx.x * 8;
    const int col = tid & 127;
    const int rh  = tid >> 7;

    const int sr  = tid >> 5;
    const int sc4 = (tid & 31) * 4;
    const int ra  = min(r0 + sr, M - 1);
    // reduce partials + bias + relu during staging
    float4 s = {0.f, 0.f, 0.f, 0.f};
    for (int sk = 0; sk < SK; sk++) {
        float4 v = *(const float4*)(Cp + ((size_t)sk * M + ra) * 128 + sc4);
        s.x += v.x; s.y += v.y; s.z += v.z; s.w += v.w;
    }
    float4 bb = *(const float4*)(b1v + sc4);
    s.x = fmaxf(s.x + bb.x, 0.f);
    s.y = fmaxf(s.y + bb.y, 0.f);
    s.z = fmaxf(s.z + bb.z, 0.f);
    s.w = fmaxf(s.w + bb.w, 0.f);
    *(float4*)&As[sr * 128 + sc4] = s;

    float acc[4] = {};
    for (int kc = 0; kc < 128; kc += 64) {
#pragma unroll
        for (int l = 0; l < 8; l++) {
            int idx = tid + l * 256;
            int wr  = idx >> 5;
            int wc  = (idx & 31) * 4;
            *(float4*)&Ws[wr * 128 + wc] =
                *(const float4*)(W + (size_t)(kc + wr) * 128 + wc);
        }
        __syncthreads();
        for (int k = 0; k < 64; k += 4) {
            float w0 = Ws[(k + 0) * 128 + col];
            float w1 = Ws[(k + 1) * 128 + col];
            float w2 = Ws[(k + 2) * 128 + col];
            float w3 = Ws[(k + 3) * 128 + col];
#pragma unroll
            for (int r = 0; r < 4; r++) {
                float4 av = *(const float4*)&As[(rh * 4 + r) * 128 + kc + k];
                acc[r] = fmaf(av.x, w0, acc[r]);
                acc[r] = fmaf(av.y, w1, acc[r]);
                acc[r] = fmaf(av.z, w2, acc[r]);
                acc[r] = fmaf(av.w, w3, acc[r]);
            }
        }
        __syncthreads();
    }
    float b2 = b2v[col];
#pragma unroll
    for (int r = 0; r < 4; r++) {
        int row = r0 + rh * 4 + r;
        if (row < M) Cout[(size_t)row * 128 + col] = fmaxf(acc[r] + b2, 0.f);
    }
}

// Bucketed aggregation pass A: deg[dst]++ for edges with dst < nD.
__global__ __launch_bounds__(256) void k_deg(const int* __restrict__ ei,
                                             int* __restrict__ deg, int E, int nD) {
    int e = blockIdx.x * 256 + threadIdx.x;
    if (e >= E) return;
    int dst = ei[E + e];
    if (dst < nD) atomicAdd(deg + dst, 1);
}

// Pass B: single-block Hillis-Steele scan -> exclusive offsets + cursor copy.
__global__ __launch_bounds__(1024) void k_scan(const int* __restrict__ deg,
                                               int* __restrict__ off,
                                               int* __restrict__ cursor, int nD) {
    __shared__ int s[1024];
    int t = threadIdx.x;
    int v = (t < nD) ? deg[t] : 0;
    s[t] = v;
    __syncthreads();
    for (int o = 1; o < 1024; o <<= 1) {
        int add = (t >= o) ? s[t - o] : 0;
        __syncthreads();
        s[t] += add;
        __syncthreads();
    }
    int excl = s[t] - v;
    if (t < nD) {
        off[t]    = excl;
        cursor[t] = excl;
    }
    if (t == nD - 1) off[nD] = s[t];
}

// Pass C: scatter src indices of surviving edges into per-dst buckets.
__global__ __launch_bounds__(256) void k_fill(const int* __restrict__ ei,
                                              int* __restrict__ cursor,
                                              int* __restrict__ srcIdx, int E, int nD) {
    int e = blockIdx.x * 256 + threadIdx.x;
    if (e >= E) return;
    int dst = ei[E + e];
    if (dst >= nD) return;
    int pos = atomicAdd(cursor + dst, 1);
    srcIdx[pos] = ei[e];
}

// Pass D: one block per dst drug; src rows gathered from xFd (drugs) or pE
// (proteins) directly — no concatenated xF buffer, no 10 MB memcpy.
__global__ __launch_bounds__(128) void k_agg(const int* __restrict__ off,
                                             const int* __restrict__ srcIdx,
                                             const float* __restrict__ xFd,
                                             const float* __restrict__ pE,
                                             float* __restrict__ agg,
                                             float* __restrict__ cnt, int nD) {
    int d = blockIdx.x;
    int c = threadIdx.x;
    int s0 = off[d], s1 = off[d + 1];
    float acc = 0.f;
    for (int j = s0; j < s1; j++) {
        int src = srcIdx[j];
        const float* base = (src < nD) ? (xFd + (size_t)src * 128)
                                       : (pE + (size_t)(src - nD) * 128);
        acc += base[c];
    }
    agg[(size_t)d * 128 + c] = acc;
    if (c == 0) cnt[d] = (float)(s1 - s0);
}

// fX = relu((agg/max(cnt,1)) @ Wl + bl + xFd @ Wr). Wl/Wr staged in LDS as
// 32-row panels (4 phases). 8 rows/block.
__global__ __launch_bounds__(256) void k_sage(const float* __restrict__ agg,
                                              const float* __restrict__ cnt,
                                              const float* __restrict__ xFd,
                                              const float* __restrict__ Wl,
                                              const float* __restrict__ bl,
                                              const float* __restrict__ Wr,
                                              float* __restrict__ fX, int M) {
    __shared__ float ms[8 * 128];
    __shared__ float xs[8 * 128];
    __shared__ float Wls[32 * 128];
    __shared__ float Wrs[32 * 128];
    const int tid = threadIdx.x;
    const int r0  = blockIdx.x * 8;
    const int col = tid & 127;
    const int rh  = tid >> 7;

    const int sr  = tid >> 5;
    const int sc4 = (tid & 31) * 4;
    const int ra  = min(r0 + sr, M - 1);
    float inv = 1.0f / fmaxf(cnt[ra], 1.0f);
    float4 av = *(const float4*)(agg + (size_t)ra * 128 + sc4);
    av.x *= inv; av.y *= inv; av.z *= inv; av.w *= inv;
    *(float4*)&ms[sr * 128 + sc4] = av;
    *(float4*)&xs[sr * 128 + sc4] = *(const float4*)(xFd + (size_t)ra * 128 + sc4);

    float acc[4] = {};
    for (int kc = 0; kc < 128; kc += 32) {
#pragma unroll
        for (int l = 0; l < 4; l++) {
            int idx = tid + l * 256;  // float4 index 0..1023
            int wr  = idx >> 5;       // 0..31
            int wc  = (idx & 31) * 4;
            *(float4*)&Wls[wr * 128 + wc] =
                *(const float4*)(Wl + (size_t)(kc + wr) * 128 + wc);
            *(float4*)&Wrs[wr * 128 + wc] =
                *(const float4*)(Wr + (size_t)(kc + wr) * 128 + wc);
        }
        __syncthreads();
        for (int u = 0; u < 32; u++) {
            float wl = Wls[u * 128 + col];
            float wr = Wrs[u * 128 + col];
#pragma unroll
            for (int r = 0; r < 4; r++) {
                acc[r] = fmaf(ms[(rh * 4 + r) * 128 + kc + u], wl, acc[r]);
                acc[r] = fmaf(xs[(rh * 4 + r) * 128 + kc + u], wr, acc[r]);
            }
        }
        __syncthreads();
    }
    float bb = bl[col];
#pragma unroll
    for (int r = 0; r < 4; r++) {
        int row = r0 + rh * 4 + r;
        if (row < M) fX[(size_t)row * 128 + col] = fmaxf(acc[r] + bb, 0.f);
    }
}

// Gather outW2[:, sampleSes] into padded (128 x 512) + outB2[sampleSes] into 512.
__global__ __launch_bounds__(256) void k_w2g(const float* __restrict__ oW2,
                                             const float* __restrict__ oB2,
                                             const int* __restrict__ sSes,
                                             float* __restrict__ W2p,
                                             float* __restrict__ B2p, int nSe, int S) {
    int t = blockIdx.x * 256 + threadIdx.x;
    if (t < 128 * 512) {
        int k = t >> 9, j = t & 511;
        W2p[t] = (j < S) ? oW2[(size_t)k * nSe + sSes[j]] : 0.f;
    } else {
        int j = t - 128 * 512;
        if (j < 512) B2p[j] = (j < S) ? oB2[sSes[j]] : 0.f;
    }
}

// Generic small GEMM (used for M2 = outW1 @ W2p): C(M x 512) = A(M x 128) @ B.
__global__ __launch_bounds__(256) void k_g16(const float* __restrict__ A,
                                             const float* __restrict__ B,
                                             float* __restrict__ C, int M,
                                             int ldb, int ldc) {
    __shared__ float As[16 * 128];
    const int tid = threadIdx.x;
    const int r0  = blockIdx.x * 16;
    const int cb  = blockIdx.y;
    const int c4  = (tid & 31) * 4;
    const int rg  = tid >> 5;

#pragma unroll
    for (int l = 0; l < 2; l++) {
        int idx = tid + l * 256;
        int row = idx >> 5, cc = (idx & 31) * 4;
        int ra  = min(r0 + row, M - 1);
        *(float4*)&As[row * 128 + cc] = *(const float4*)(A + (size_t)ra * 128 + cc);
    }
    __syncthreads();

    const float* Bp = B + cb * 128 + c4;
    float acc[2][4] = {};
    for (int k = 0; k < 128; k += 4) {
        float4 a0 = *(const float4*)&As[(rg * 2 + 0) * 128 + k];
        float4 a1 = *(const float4*)&As[(rg * 2 + 1) * 128 + k];
        const float* pa0 = &a0.x;
        const float* pa1 = &a1.x;
#pragma unroll
        for (int u = 0; u < 4; u++) {
            float4 wv = *(const float4*)(Bp + (size_t)(k + u) * ldb);
            float v0 = pa0[u], v1 = pa1[u];
            acc[0][0] = fmaf(v0, wv.x, acc[0][0]);
            acc[0][1] = fmaf(v0, wv.y, acc[0][1]);
            acc[0][2] = fmaf(v0, wv.z, acc[0][2]);
            acc[0][3] = fmaf(v0, wv.w, acc[0][3]);
            acc[1][0] = fmaf(v1, wv.x, acc[1][0]);
            acc[1][1] = fmaf(v1, wv.y, acc[1][1]);
            acc[1][2] = fmaf(v1, wv.z, acc[1][2]);
            acc[1][3] = fmaf(v1, wv.w, acc[1][3]);
        }
    }
#pragma unroll
    for (int r = 0; r < 2; r++) {
        int row = r0 + rg * 2 + r;
        if (row < M) {
            float4 o = {acc[r][0], acc[r][1], acc[r][2], acc[r][3]};
            *(float4*)(C + (size_t)row * ldc + cb * 128 + c4) = o;
        }
    }
}

// Cvec[j] = sum_k oB1[k] * W2p[k][j] + B2p[j], j in [0,512)
__global__ __launch_bounds__(256) void k_cvec(const float* __restrict__ oB1,
                                              const float* __restrict__ W2p,
                                              const float* __restrict__ B2p,
                                              float* __restrict__ Cvec) {
    int j = blockIdx.x * 256 + threadIdx.x;
    if (j >= 512) return;
    float s = B2p[j];
    for (int k = 0; k < 128; k++) s = fmaf(oB1[k], W2p[k * 512 + j], s);
    Cvec[j] = s;
}

// PPQQ = fX @ [M2_hi | M2_lo] with Cvec folded into the PP half.
// grid (ceil(M/16), 8): cb 0..3 -> PP (+Cvec), cb 4..7 -> QQ. B staged in LDS.
__global__ __launch_bounds__(256) void k_pq(const float* __restrict__ A,
                                            const float* __restrict__ M2,
                                            const float* __restrict__ Cvec,
                                            float* __restrict__ C, int M) {
    __shared__ float As[16 * 128];
    __shared__ float Bs[64 * 128];
    const int tid = threadIdx.x;
    const int r0  = blockIdx.x * 16;
    const int cb  = blockIdx.y;  // 0..7
    const int c4  = (tid & 31) * 4;
    const int rg  = tid >> 5;

    const float* B = M2 + (size_t)(cb >> 2) * (128 * 512) + (cb & 3) * 128;

#pragma unroll
    for (int l = 0; l < 2; l++) {
        int idx = tid + l * 256;
        int row = idx >> 5, cc = (idx & 31) * 4;
        int ra  = min(r0 + row, M - 1);
        *(float4*)&As[row * 128 + cc] = *(const float4*)(A + (size_t)ra * 128 + cc);
    }

    float acc[2][4] = {};
    for (int kc = 0; kc < 128; kc += 64) {
#pragma unroll
        for (int l = 0; l < 8; l++) {
            int idx = tid + l * 256;  // float4 index 0..2047
            int wr  = idx >> 5;       // 0..63
            int wc  = (idx & 31) * 4;
            *(float4*)&Bs[wr * 128 + wc] =
                *(const float4*)(B + (size_t)(kc + wr) * 512 + wc);
        }
        __syncthreads();
        for (int k = 0; k < 64; k += 4) {
            float4 a0 = *(const float4*)&As[(rg * 2 + 0) * 128 + kc + k];
            float4 a1 = *(const float4*)&As[(rg * 2 + 1) * 128 + kc + k];
            const float* pa0 = &a0.x;
            const float* pa1 = &a1.x;
#pragma unroll
            for (int u = 0; u < 4; u++) {
                float4 wv = *(const float4*)&Bs[(k + u) * 128 + c4];
                float v0 = pa0[u], v1 = pa1[u];
                acc[0][0] = fmaf(v0, wv.x, acc[0][0]);
                acc[0][1] = fmaf(v0, wv.y, acc[0][1]);
                acc[0][2] = fmaf(v0, wv.z, acc[0][2]);
                acc[0][3] = fmaf(v0, wv.w, acc[0][3]);
                acc[1][0] = fmaf(v1, wv.x, acc[1][0]);
                acc[1][1] = fmaf(v1, wv.y, acc[1][1]);
                acc[1][2] = fmaf(v1, wv.z, acc[1][2]);
                acc[1][3] = fmaf(v1, wv.w, acc[1][3]);
            }
        }
        __syncthreads();
    }
    float4 cv = {0.f, 0.f, 0.f, 0.f};
    if (cb < 4) cv = *(const float4*)(Cvec + cb * 128 + c4);
    int colbase = (cb >> 2) * 512 + (cb & 3) * 128 + c4;
#pragma unroll
    for (int r = 0; r < 2; r++) {
        int row = r0 + rg * 2 + r;
        if (row < M) {
            float4 o = {acc[r][0] + cv.x, acc[r][1] + cv.y, acc[r][2] + cv.z,
                        acc[r][3] + cv.w};
            *(float4*)(C + (size_t)row * 1024 + colbase) = o;
        }
    }
}

// out[t] = hshrink(PP'[a] + QQ[b]); Cvec already folded into PP'.
__global__ __launch_bounds__(256) void k_final(const int* __restrict__ tpl,
                                               const float* __restrict__ PPQQ,
                                               float* __restrict__ out, int T, int S) {
    int t = blockIdx.x * 2 + (threadIdx.x >> 7);
    int i = threadIdx.x & 127;
    int nf4 = S >> 2;  // 125 for S=500
    if (t >= T || i >= nf4) return;
    int a = tpl[2 * t];
    int b = tpl[2 * t + 1];
    float4 p = ((const float4*)(PPQQ + (size_t)a * 1024))[i];
    float4 q = ((const float4*)(PPQQ + (size_t)b * 1024 + 512))[i];
    float o0 = hshrink(p.x + q.x);
    float o1 = hshrink(p.y + q.y);
    float o2 = hshrink(p.z + q.z);
    float o3 = hshrink(p.w + q.w);
    float* po = out + (size_t)t * S + i * 4;
    // nontemporal: keep the 4 MB PPQQ working set resident in L2
    __builtin_nontemporal_store(o0, po + 0);
    __builtin_nontemporal_store(o1, po + 1);
    __builtin_nontemporal_store(o2, po + 2);
    __builtin_nontemporal_store(o3, po + 3);
}

extern "C" void kernel_launch(void* const* d_in, const int* in_sizes, int n_in,
                              void* d_out, int out_size, void* d_ws, size_t ws_size,
                              hipStream_t stream) {
    const float* dF   = (const float*)d_in[0];
    const int*   ei   = (const int*)d_in[1];
    const int*   tpl  = (const int*)d_in[2];
    const int*   sSes = (const int*)d_in[3];
    const float* W1   = (const float*)d_in[4];
    const float* b1   = (const float*)d_in[5];
    const float* W2   = (const float*)d_in[6];
    const float* b2   = (const float*)d_in[7];
    const float* pE   = (const float*)d_in[8];
    const float* sWl  = (const float*)d_in[9];
    const float* sBl  = (const float*)d_in[10];
    const float* sWr  = (const float*)d_in[11];
    const float* oW1  = (const float*)d_in[12];
    const float* oB1  = (const float*)d_in[13];
    const float* oW2  = (const float*)d_in[14];
    const float* oB2  = (const float*)d_in[15];

    const int D    = 128;
    const int F    = in_sizes[4] / D;   // 2048
    const int nD   = in_sizes[0] / F;   // 1000
    const int E    = in_sizes[1] / 2;   // 640000
    const int T    = in_sizes[2] / 2;   // 150000
    const int S    = in_sizes[3];       // 500
    const int nSe  = in_sizes[15];      // 964
    const int SK   = 4;                 // split-K for layer-1 MLP

    float* ws   = (float*)d_ws;
    float* xFd  = ws;                                // nD*128  (drug embeddings)
    float* h1p  = xFd + (size_t)nD * D;              // SK*nD*128 (layer-1 partials)
    float* agg  = h1p + (size_t)SK * nD * D;         // nD*128
    float* cnt  = agg + (size_t)nD * D;              // nD (padded to 1024)
    float* fX   = cnt + 1024;                        // nD*128
    float* W2p  = fX + (size_t)nD * D;               // 128*512
    float* B2p  = W2p + 128 * 512;                   // 512
    float* M2   = B2p + 512;                         // 256*512
    float* Cvec = M2 + 256 * 512;                    // 512
    float* PPQQ = Cvec + 512;                        // nD*1024
    int* deg    = (int*)(PPQQ + (size_t)nD * 1024);  // 1024
    int* off    = deg + 1024;                        // 1025
    int* cursor = off + 1025;                        // 1024
    int* srcIdx = cursor + 1024;                     // <= E

    // layer-1 split-K partials; layer-2 fuses the reduction + bias + relu
    {
        dim3 g((nD + 15) / 16, SK);
        k_mlp1<<<g, 256, 0, stream>>>(dF, W1, h1p, nD, F, F / SK);
    }
    k_mlp2<<<(nD + 7) / 8, 256, 0, stream>>>(h1p, b1, W2, b2, xFd, nD, SK);
    // bucketed edge aggregation
    hipMemsetAsync(deg, 0, 1024 * sizeof(int), stream);
    k_deg<<<(E + 255) / 256, 256, 0, stream>>>(ei, deg, E, nD);
    k_scan<<<1, 1024, 0, stream>>>(deg, off, cursor, nD);
    k_fill<<<(E + 255) / 256, 256, 0, stream>>>(ei, cursor, srcIdx, E, nD);
    k_agg<<<nD, 128, 0, stream>>>(off, srcIdx, xFd, pE, agg, cnt, nD);
    // SAGE rows 0..nD-1 -> fX
    k_sage<<<(nD + 7) / 8, 256, 0, stream>>>(agg, cnt, xFd, sWl, sBl, sWr, fX, nD);
    // gather sampled outW2 columns (padded to 512)
    k_w2g<<<(128 * 512 + 512 + 255) / 256, 256, 0, stream>>>(oW2, oB2, sSes, W2p, B2p,
                                                             nSe, S);
    // M2 = outW1 (256x128) @ W2p (128x512)
    {
        dim3 g((256 + 15) / 16, 4);
        k_g16<<<g, 256, 0, stream>>>(oW1, W2p, M2, 256, 512, 512);
    }
    // Cvec = oB1 @ W2p + B2p
    k_cvec<<<2, 256, 0, stream>>>(oB1, W2p, B2p, Cvec);
    // PPQQ (PP' = fX@M2_hi + Cvec, QQ = fX@M2_lo) in one launch
    {
        dim3 g((nD + 15) / 16, 8);
        k_pq<<<g, 256, 0, stream>>>(fX, M2, Cvec, PPQQ, nD);
    }
    // final streaming epilogue
    k_final<<<(T + 1) / 2, 256, 0, stream>>>(tpl, PPQQ, (float*)d_out, T, S);
}